// Round 2
// baseline (670.895 us; speedup 1.0000x reference)
//
#include <hip/hip_runtime.h>
#include <hip/hip_bf16.h>

// NT-Xent (CLIP) loss, N=16384 D=256 fp32 in, 3 fp32 out.
// loss_vu = mean_i( log(sum_j exp(sim_ij)) - sim_ii ), sim = (v̂·û^T)/T
// Logits bounded by 1/T=14.29 -> no max subtraction needed for exp stability.
//
// R2: XOR-swizzled LDS (zero bank conflicts), per-row diag array. 237us.
// R3: gload_lds staging -- REGRESSED (280us): serial stage->drain->compute
//     structure can't hide the load latency; gload_lds only removed the
//     (cheap) VGPR round-trip while keeping the (expensive) serial drain.
// R4: T14 async-STAGE split, reg-staged (reg-staging is T14's prereq):
//     issue tile t+1's global loads into VGPRs BEFORE computing tile t;
//     the ~300cyc L2 latency hides under the 32-MFMA compute phase, so the
//     vmcnt drain at the post-compute barrier is ~free. Single 32KB LDS
//     buffer (WAR-safe via the two existing barriers), keeping LDS
//     occupancy headroom to overlap per-block epilogues.
//     Keeps from R3: exp2-folded epilogue, rowsum/colsum zeroing in K1.

#define D_DIM 256
#define BM 128
#define BN 128
#define BK 64

constexpr float INV_T = 1.0f / 0.07f;
constexpr float EXP2_SCALE = 1.44269504088896340736f / 0.07f;  // log2(e)/T

typedef __bf16 bf16x8 __attribute__((ext_vector_type(8)));
typedef float f32x4 __attribute__((ext_vector_type(4)));

// ---------------------------------------------------------------------------
// Kernel 1: L2-normalize (fp32 -> bf16), one WAVE per row (4 rows/block).
//           Writes per-row diag contribution v̂_i·û_i to diagarr (no atomic).
//           Also zeroes rowsum/colsum for this row (replaces memset; safe
//           because kernel-boundary order guarantees zeros before K2).
// ---------------------------------------------------------------------------
__global__ __launch_bounds__(256) void normalize_kernel(
    const float* __restrict__ img, const float* __restrict__ txt,
    __hip_bfloat16* __restrict__ Vb, __hip_bfloat16* __restrict__ Ub,
    float* __restrict__ diagarr, float* __restrict__ rowsum,
    float* __restrict__ colsum) {
  const int wave = threadIdx.x >> 6;
  const int lane = threadIdx.x & 63;
  const int row = blockIdx.x * 4 + wave;
  const size_t base = (size_t)row * D_DIM + lane * 4;

  const float4 iv = *reinterpret_cast<const float4*>(&img[base]);
  const float4 tv = *reinterpret_cast<const float4*>(&txt[base]);

  float a = iv.x * iv.x + iv.y * iv.y + iv.z * iv.z + iv.w * iv.w;
  float b = tv.x * tv.x + tv.y * tv.y + tv.z * tv.z + tv.w * tv.w;
#pragma unroll
  for (int off = 1; off < 64; off <<= 1) {
    a += __shfl_xor(a, off, 64);
    b += __shfl_xor(b, off, 64);
  }
  const float si = 1.0f / fmaxf(sqrtf(a), 1e-8f);
  const float st = 1.0f / fmaxf(sqrtf(b), 1e-8f);
  const float4 v = {iv.x * si, iv.y * si, iv.z * si, iv.w * si};
  const float4 u = {tv.x * st, tv.y * st, tv.z * st, tv.w * st};

  __hip_bfloat16 vb4[4] = {__float2bfloat16(v.x), __float2bfloat16(v.y),
                           __float2bfloat16(v.z), __float2bfloat16(v.w)};
  __hip_bfloat16 ub4[4] = {__float2bfloat16(u.x), __float2bfloat16(u.y),
                           __float2bfloat16(u.z), __float2bfloat16(u.w)};
  *reinterpret_cast<uint2*>(&Vb[base]) = *reinterpret_cast<uint2*>(vb4);
  *reinterpret_cast<uint2*>(&Ub[base]) = *reinterpret_cast<uint2*>(ub4);

  float d = v.x * u.x + v.y * u.y + v.z * u.z + v.w * u.w;
#pragma unroll
  for (int off = 1; off < 64; off <<= 1) d += __shfl_xor(d, off, 64);
  if (lane == 0) {
    diagarr[row] = d;
    rowsum[row] = 0.0f;
    colsum[row] = 0.0f;
  }
}

// ---------------------------------------------------------------------------
// Kernel 2: tiled bf16 MFMA GEMM over sim = V·U^T, online exp-sum per row
//           and per column. 128x128 tile/block, 4 waves of 64x64.
// LDS layout XOR-swizzled: 16B chunk c8 of row r stored at chunk (c8 ^ (r&7)).
//   - staging writes: per wave, rows l>>3 (0..7) x chunks l&7 -> p=c8^row
//     spans 0..7 per row-group -> all 32 banks, conflict-free.
//   - frag reads: 16 lanes read rows base+l15 at chunk c8a -> p=c8a^(l15&7)
//     spans 0..7 per 8 lanes -> 2 lanes/bank = free (m136).
// Pipeline (T14): loads for tile t+1 issue before tile t's MFMA cluster;
//   compute covers the L2-hit latency; writes land after the WAR barrier.
// A-frag (16x16x32): A[m=lane&15][k=quad*8+j]; B symmetric (U row-major).
// C/D: col=lane&15, row=quad*4+reg (m89/m91-verified).
// ---------------------------------------------------------------------------
__global__ __launch_bounds__(256) void gemm_lse_kernel(
    const __hip_bfloat16* __restrict__ V, const __hip_bfloat16* __restrict__ U,
    float* __restrict__ rowsum, float* __restrict__ colsum) {
  __shared__ __align__(16) unsigned short As[BM * BK];  // 16 KB
  __shared__ __align__(16) unsigned short Bs[BN * BK];  // 16 KB

  const int tid = threadIdx.x;
  const int lane = tid & 63;
  const int wave = tid >> 6;
  const int wm = wave >> 1;   // wave row (0..1)
  const int wn = wave & 1;    // wave col (0..1)
  const int quad = lane >> 4;
  const int l15 = lane & 15;
  const int sw = l15 & 7;     // read-swizzle factor (= frag row & 7)
  const int ibase = blockIdx.y * BM;
  const int jbase = blockIdx.x * BN;

  f32x4 acc[4][4] = {};

  // Staging registers (live across the compute phase -- that's the point).
  uint4 ra[4], rb[4];

  auto LOAD = [&](int kk) {
#pragma unroll
    for (int q = 0; q < 4; ++q) {
      const int chunk = q * 256 + tid;  // [0,1024)
      const int row = chunk >> 3;       // 8 x 16B per 64-col row
      const int c8 = chunk & 7;
      ra[q] = *reinterpret_cast<const uint4*>(
          &V[(size_t)(ibase + row) * D_DIM + kk + c8 * 8]);
      rb[q] = *reinterpret_cast<const uint4*>(
          &U[(size_t)(jbase + row) * D_DIM + kk + c8 * 8]);
    }
  };
  auto WRITE = [&]() {
#pragma unroll
    for (int q = 0; q < 4; ++q) {
      const int chunk = q * 256 + tid;
      const int row = chunk >> 3;
      const int c8 = chunk & 7;
      const int dst = row * BK + ((c8 ^ (row & 7)) << 3);  // swizzled
      *reinterpret_cast<uint4*>(&As[dst]) = ra[q];
      *reinterpret_cast<uint4*>(&Bs[dst]) = rb[q];
    }
  };

  LOAD(0);
  WRITE();
  __syncthreads();

#pragma unroll
  for (int t = 0; t < 4; ++t) {
    if (t < 3) LOAD((t + 1) * BK);  // issue early: latency hides under MFMA

#pragma unroll
    for (int ks = 0; ks < BK; ks += 32) {
      const int c8a = (ks >> 3) + quad;          // logical 16B chunk
      const int pc = ((c8a ^ sw) << 3);          // swizzled short offset
      bf16x8 af[4], bfr[4];
#pragma unroll
      for (int mi = 0; mi < 4; ++mi)
        af[mi] = *reinterpret_cast<const bf16x8*>(
            &As[(wm * 64 + mi * 16 + l15) * BK + pc]);
#pragma unroll
      for (int ni = 0; ni < 4; ++ni)
        bfr[ni] = *reinterpret_cast<const bf16x8*>(
            &Bs[(wn * 64 + ni * 16 + l15) * BK + pc]);
#pragma unroll
      for (int mi = 0; mi < 4; ++mi)
#pragma unroll
        for (int ni = 0; ni < 4; ++ni)
          acc[mi][ni] = __builtin_amdgcn_mfma_f32_16x16x32_bf16(
              af[mi], bfr[ni], acc[mi][ni], 0, 0, 0);
    }
    __syncthreads();  // all waves done READING As/Bs (WAR guard)
    if (t < 3) {
      WRITE();        // loads landed during compute; drain is ~free
      __syncthreads();
    }
  }

  // ---- epilogue: exp + row/col reduction ----
  // acc[mi][ni][r]: row = wm*64+mi*16+quad*4+r, col = wn*64+ni*16+l15.
  // exp(acc/T) = exp2(acc * log2e/T): single mul + v_exp per element.
#pragma unroll
  for (int mi = 0; mi < 4; ++mi)
#pragma unroll
    for (int ni = 0; ni < 4; ++ni)
#pragma unroll
      for (int r = 0; r < 4; ++r)
        acc[mi][ni][r] = __builtin_amdgcn_exp2f(acc[mi][ni][r] * EXP2_SCALE);

  // Reuse As as fp32 scratch: rowbuf[128], colbuf[128].
  float* rowbuf = reinterpret_cast<float*>(As);
  float* colbuf = rowbuf + BM;
  reinterpret_cast<float*>(As)[tid] = 0.0f;  // zero 256 floats
  __syncthreads();

  // Row sums: reduce across 16 cols (lanes quad*16..quad*16+15), then the
  // two wn halves meet in LDS.
#pragma unroll
  for (int mi = 0; mi < 4; ++mi) {
#pragma unroll
    for (int r = 0; r < 4; ++r) {
      float rs = acc[mi][0][r] + acc[mi][1][r] + acc[mi][2][r] + acc[mi][3][r];
      rs += __shfl_xor(rs, 1, 64);
      rs += __shfl_xor(rs, 2, 64);
      rs += __shfl_xor(rs, 4, 64);
      rs += __shfl_xor(rs, 8, 64);
      if (l15 == 0)
        atomicAdd(&rowbuf[wm * 64 + mi * 16 + quad * 4 + r], rs);
    }
  }
  // Col sums: reduce across 16 rows (quads), two wm halves meet in LDS.
#pragma unroll
  for (int ni = 0; ni < 4; ++ni) {
    float cs = 0.0f;
#pragma unroll
    for (int mi = 0; mi < 4; ++mi)
      cs += acc[mi][ni][0] + acc[mi][ni][1] + acc[mi][ni][2] + acc[mi][ni][3];
    cs += __shfl_xor(cs, 16, 64);
    cs += __shfl_xor(cs, 32, 64);
    if (lane < 16)
      atomicAdd(&colbuf[wn * 64 + ni * 16 + l15], cs);
  }
  __syncthreads();

  if (tid < BM)
    atomicAdd(&rowsum[ibase + tid], rowbuf[tid]);
  else
    atomicAdd(&colsum[jbase + tid - BM], colbuf[tid - BM]);
}

// ---------------------------------------------------------------------------
// Kernel 3: finalize — mean(log(rowsum)), mean(log(colsum)), mean(diag).
// ---------------------------------------------------------------------------
__global__ __launch_bounds__(1024) void finalize_kernel(
    const float* __restrict__ rowsum, const float* __restrict__ colsum,
    const float* __restrict__ diagarr, float* __restrict__ out, int n) {
  __shared__ float sh[48];
  float sr = 0.0f, sc = 0.0f, sd = 0.0f;
  for (int i = threadIdx.x; i < n; i += 1024) {
    sr += logf(rowsum[i]);
    sc += logf(colsum[i]);
    sd += diagarr[i];
  }
#pragma unroll
  for (int off = 1; off < 64; off <<= 1) {
    sr += __shfl_xor(sr, off, 64);
    sc += __shfl_xor(sc, off, 64);
    sd += __shfl_xor(sd, off, 64);
  }
  const int w = threadIdx.x >> 6, lane = threadIdx.x & 63;
  if (lane == 0) { sh[w] = sr; sh[16 + w] = sc; sh[32 + w] = sd; }
  __syncthreads();
  if (threadIdx.x == 0) {
    float tr = 0.0f, tc = 0.0f, td = 0.0f;
#pragma unroll
    for (int i = 0; i < 16; ++i) {
      tr += sh[i]; tc += sh[16 + i]; td += sh[32 + i];
    }
    const float invN = 1.0f / (float)n;
    const float dm = td * INV_T * invN;   // mean diag logit
    const float lvu = tr * invN - dm;
    const float luv = tc * invN - dm;
    out[0] = 0.5f * lvu + 0.5f * luv;  // WEIGHT = 0.5
    out[1] = lvu;
    out[2] = luv;
  }
}

extern "C" void kernel_launch(void* const* d_in, const int* in_sizes, int n_in,
                              void* d_out, int out_size, void* d_ws, size_t ws_size,
                              hipStream_t stream) {
  const float* img = (const float*)d_in[0];
  const float* txt = (const float*)d_in[1];
  float* out = (float*)d_out;
  const int N = in_sizes[0] / D_DIM;  // 16384

  char* ws = (char*)d_ws;
  __hip_bfloat16* Vb = (__hip_bfloat16*)ws;
  __hip_bfloat16* Ub = (__hip_bfloat16*)(ws + (size_t)N * D_DIM * 2);
  float* rowsum = (float*)(ws + (size_t)N * D_DIM * 4);
  float* colsum = rowsum + N;
  float* diagarr = colsum + N;

  // rowsum/colsum zeroed inside normalize_kernel (ws poisoned 0xAA pre-launch)
  normalize_kernel<<<N / 4, 256, 0, stream>>>(img, txt, Vb, Ub, diagarr,
                                              rowsum, colsum);

  dim3 grid(N / BN, N / BM);
  gemm_lse_kernel<<<grid, 256, 0, stream>>>(Vb, Ub, rowsum, colsum);

  finalize_kernel<<<1, 1024, 0, stream>>>(rowsum, colsum, diagarr, out, N);
}

// Round 3
// 293.908 us; speedup vs baseline: 2.2827x; 2.2827x over previous
//
#include <hip/hip_runtime.h>
#include <hip/hip_bf16.h>

// NT-Xent (CLIP) loss, N=16384 D=256 fp32 in, 3 fp32 out.
// loss_vu = mean_i( log(sum_j exp(sim_ij)) - sim_ii ), sim = (v̂·û^T)/T
// Logits bounded by 1/T=14.29 -> no max subtraction needed for exp stability.
//
// R2: XOR-swizzled LDS (zero bank conflicts), per-row diag array. 237us.
// R3: gload_lds staging -- REGRESSED (280us): serial stage->drain->compute.
// R4: T14 via lambdas capturing uint4 ra[4]/rb[4] by reference -- REGRESSED
//     (635us): lambda capture defeated SROA, staging arrays escaped to
//     SCRATCH (WRITE_SIZE 16MB->910MB, FETCH 37->175MB). Concept untested.
// R5: T14 done right: eight NAMED uint4 staging scalars, macro-expanded
//     load/store (no arrays, no lambdas -- nothing can escape to scratch).
//     Issue tile t+1's global loads BEFORE tile t's MFMA cluster; ~300cyc
//     L2 latency hides under compute; post-barrier ds_write + barrier.
//     Single 32KB LDS buffer (WAR-safe via the two barriers).
//     Verification gate: WRITE_SIZE must return to ~16MB.

#define D_DIM 256
#define BM 128
#define BN 128
#define BK 64

constexpr float INV_T = 1.0f / 0.07f;
constexpr float EXP2_SCALE = 1.44269504088896340736f / 0.07f;  // log2(e)/T

typedef __bf16 bf16x8 __attribute__((ext_vector_type(8)));
typedef float f32x4 __attribute__((ext_vector_type(4)));

// ---------------------------------------------------------------------------
// Kernel 1: L2-normalize (fp32 -> bf16), one WAVE per row (4 rows/block).
//           Writes per-row diag contribution v̂_i·û_i to diagarr (no atomic).
//           Also zeroes rowsum/colsum for this row (replaces memset).
// ---------------------------------------------------------------------------
__global__ __launch_bounds__(256) void normalize_kernel(
    const float* __restrict__ img, const float* __restrict__ txt,
    __hip_bfloat16* __restrict__ Vb, __hip_bfloat16* __restrict__ Ub,
    float* __restrict__ diagarr, float* __restrict__ rowsum,
    float* __restrict__ colsum) {
  const int wave = threadIdx.x >> 6;
  const int lane = threadIdx.x & 63;
  const int row = blockIdx.x * 4 + wave;
  const size_t base = (size_t)row * D_DIM + lane * 4;

  const float4 iv = *reinterpret_cast<const float4*>(&img[base]);
  const float4 tv = *reinterpret_cast<const float4*>(&txt[base]);

  float a = iv.x * iv.x + iv.y * iv.y + iv.z * iv.z + iv.w * iv.w;
  float b = tv.x * tv.x + tv.y * tv.y + tv.z * tv.z + tv.w * tv.w;
#pragma unroll
  for (int off = 1; off < 64; off <<= 1) {
    a += __shfl_xor(a, off, 64);
    b += __shfl_xor(b, off, 64);
  }
  const float si = 1.0f / fmaxf(sqrtf(a), 1e-8f);
  const float st = 1.0f / fmaxf(sqrtf(b), 1e-8f);
  const float4 v = {iv.x * si, iv.y * si, iv.z * si, iv.w * si};
  const float4 u = {tv.x * st, tv.y * st, tv.z * st, tv.w * st};

  __hip_bfloat16 vb4[4] = {__float2bfloat16(v.x), __float2bfloat16(v.y),
                           __float2bfloat16(v.z), __float2bfloat16(v.w)};
  __hip_bfloat16 ub4[4] = {__float2bfloat16(u.x), __float2bfloat16(u.y),
                           __float2bfloat16(u.z), __float2bfloat16(u.w)};
  *reinterpret_cast<uint2*>(&Vb[base]) = *reinterpret_cast<uint2*>(vb4);
  *reinterpret_cast<uint2*>(&Ub[base]) = *reinterpret_cast<uint2*>(ub4);

  float d = v.x * u.x + v.y * u.y + v.z * u.z + v.w * u.w;
#pragma unroll
  for (int off = 1; off < 64; off <<= 1) d += __shfl_xor(d, off, 64);
  if (lane == 0) {
    diagarr[row] = d;
    rowsum[row] = 0.0f;
    colsum[row] = 0.0f;
  }
}

// ---------------------------------------------------------------------------
// Kernel 2: tiled bf16 MFMA GEMM over sim = V·U^T, online exp-sum per row
//           and per column. 128x128 tile/block, 4 waves of 64x64.
// LDS layout XOR-swizzled: 16B chunk c8 of row r stored at chunk (c8 ^ (r&7)).
//   - frag reads: 16 lanes read rows base+l15 at chunk c8a -> p=c8a^(l15&7)
//     spans 0..7 per 8 lanes -> 2 lanes/bank = free (m136).
// Staging addressing (per thread, all four 32-row groups):
//   r0 = tid>>3 (row-in-group), c8 = tid&7 (16B chunk in row).
//   group q covers rows q*32+r0; swizzle offset identical across q since
//   (q*32 + r0) & 7 == r0 & 7.
// Pipeline (T14): loads for tile t+1 (8 named uint4 regs) issue before
//   tile t's MFMA cluster; compute covers L2 latency; ds_writes after the
//   WAR barrier.
// A-frag (16x16x32): A[m=lane&15][k=quad*8+j]; B symmetric (U row-major).
// C/D: col=lane&15, row=quad*4+reg (m89/m91-verified).
// ---------------------------------------------------------------------------
__global__ __launch_bounds__(256) void gemm_lse_kernel(
    const __hip_bfloat16* __restrict__ V, const __hip_bfloat16* __restrict__ U,
    float* __restrict__ rowsum, float* __restrict__ colsum) {
  __shared__ __align__(16) unsigned short As[BM * BK];  // 16 KB
  __shared__ __align__(16) unsigned short Bs[BN * BK];  // 16 KB

  const int tid = threadIdx.x;
  const int lane = tid & 63;
  const int wave = tid >> 6;
  const int wm = wave >> 1;   // wave row (0..1)
  const int wn = wave & 1;    // wave col (0..1)
  const int quad = lane >> 4;
  const int l15 = lane & 15;
  const int sw = l15 & 7;     // read-swizzle factor (= frag row & 7)
  const int ibase = blockIdx.y * BM;
  const int jbase = blockIdx.x * BN;

  // Staging address bases (see header).
  const int r0 = tid >> 3;
  const int c8 = tid & 7;
  const int dbase = r0 * BK + ((c8 ^ (r0 & 7)) << 3);
  const __hip_bfloat16* Vp =
      V + (size_t)(ibase + r0) * D_DIM + c8 * 8;
  const __hip_bfloat16* Up =
      U + (size_t)(jbase + r0) * D_DIM + c8 * 8;

  // Eight named staging registers -- live across the compute phase.
  uint4 ra0, ra1, ra2, ra3, rb0, rb1, rb2, rb3;

#define LOAD_TILE(kk)                                                      \
  ra0 = *reinterpret_cast<const uint4*>(Vp + (kk));                        \
  ra1 = *reinterpret_cast<const uint4*>(Vp + 32 * D_DIM + (kk));           \
  ra2 = *reinterpret_cast<const uint4*>(Vp + 64 * D_DIM + (kk));           \
  ra3 = *reinterpret_cast<const uint4*>(Vp + 96 * D_DIM + (kk));           \
  rb0 = *reinterpret_cast<const uint4*>(Up + (kk));                        \
  rb1 = *reinterpret_cast<const uint4*>(Up + 32 * D_DIM + (kk));           \
  rb2 = *reinterpret_cast<const uint4*>(Up + 64 * D_DIM + (kk));           \
  rb3 = *reinterpret_cast<const uint4*>(Up + 96 * D_DIM + (kk));

#define WRITE_TILE()                                                       \
  *reinterpret_cast<uint4*>(&As[dbase]) = ra0;                             \
  *reinterpret_cast<uint4*>(&As[dbase + 32 * BK]) = ra1;                   \
  *reinterpret_cast<uint4*>(&As[dbase + 64 * BK]) = ra2;                   \
  *reinterpret_cast<uint4*>(&As[dbase + 96 * BK]) = ra3;                   \
  *reinterpret_cast<uint4*>(&Bs[dbase]) = rb0;                             \
  *reinterpret_cast<uint4*>(&Bs[dbase + 32 * BK]) = rb1;                   \
  *reinterpret_cast<uint4*>(&Bs[dbase + 64 * BK]) = rb2;                   \
  *reinterpret_cast<uint4*>(&Bs[dbase + 96 * BK]) = rb3;

  f32x4 acc[4][4] = {};

  LOAD_TILE(0);
  WRITE_TILE();
  __syncthreads();

#pragma unroll
  for (int t = 0; t < 4; ++t) {
    if (t < 3) {
      LOAD_TILE((t + 1) * BK);  // issue early: latency hides under MFMA
    }

#pragma unroll
    for (int ks = 0; ks < BK; ks += 32) {
      const int c8a = (ks >> 3) + quad;          // logical 16B chunk
      const int pc = ((c8a ^ sw) << 3);          // swizzled short offset
      bf16x8 af[4], bfr[4];
#pragma unroll
      for (int mi = 0; mi < 4; ++mi)
        af[mi] = *reinterpret_cast<const bf16x8*>(
            &As[(wm * 64 + mi * 16 + l15) * BK + pc]);
#pragma unroll
      for (int ni = 0; ni < 4; ++ni)
        bfr[ni] = *reinterpret_cast<const bf16x8*>(
            &Bs[(wn * 64 + ni * 16 + l15) * BK + pc]);
#pragma unroll
      for (int mi = 0; mi < 4; ++mi)
#pragma unroll
        for (int ni = 0; ni < 4; ++ni)
          acc[mi][ni] = __builtin_amdgcn_mfma_f32_16x16x32_bf16(
              af[mi], bfr[ni], acc[mi][ni], 0, 0, 0);
    }
    __syncthreads();  // all waves done READING As/Bs (WAR guard)
    if (t < 3) {
      WRITE_TILE();   // loads landed during compute; drain is ~free
      __syncthreads();
    }
  }

  // ---- epilogue: exp + row/col reduction ----
  // acc[mi][ni][r]: row = wm*64+mi*16+quad*4+r, col = wn*64+ni*16+l15.
  // exp(acc/T) = exp2(acc * log2e/T): single mul + v_exp per element.
#pragma unroll
  for (int mi = 0; mi < 4; ++mi)
#pragma unroll
    for (int ni = 0; ni < 4; ++ni)
#pragma unroll
      for (int r = 0; r < 4; ++r)
        acc[mi][ni][r] = __builtin_amdgcn_exp2f(acc[mi][ni][r] * EXP2_SCALE);

  // Reuse As as fp32 scratch: rowbuf[128], colbuf[128].
  float* rowbuf = reinterpret_cast<float*>(As);
  float* colbuf = rowbuf + BM;
  reinterpret_cast<float*>(As)[tid] = 0.0f;  // zero 256 floats
  __syncthreads();

  // Row sums: reduce across 16 cols (lanes quad*16..quad*16+15), then the
  // two wn halves meet in LDS.
#pragma unroll
  for (int mi = 0; mi < 4; ++mi) {
#pragma unroll
    for (int r = 0; r < 4; ++r) {
      float rs = acc[mi][0][r] + acc[mi][1][r] + acc[mi][2][r] + acc[mi][3][r];
      rs += __shfl_xor(rs, 1, 64);
      rs += __shfl_xor(rs, 2, 64);
      rs += __shfl_xor(rs, 4, 64);
      rs += __shfl_xor(rs, 8, 64);
      if (l15 == 0)
        atomicAdd(&rowbuf[wm * 64 + mi * 16 + quad * 4 + r], rs);
    }
  }
  // Col sums: reduce across 16 rows (quads), two wm halves meet in LDS.
#pragma unroll
  for (int ni = 0; ni < 4; ++ni) {
    float cs = 0.0f;
#pragma unroll
    for (int mi = 0; mi < 4; ++mi)
      cs += acc[mi][ni][0] + acc[mi][ni][1] + acc[mi][ni][2] + acc[mi][ni][3];
    cs += __shfl_xor(cs, 16, 64);
    cs += __shfl_xor(cs, 32, 64);
    if (lane < 16)
      atomicAdd(&colbuf[wn * 64 + ni * 16 + l15], cs);
  }
  __syncthreads();

  if (tid < BM)
    atomicAdd(&rowsum[ibase + tid], rowbuf[tid]);
  else
    atomicAdd(&colsum[jbase + tid - BM], colbuf[tid - BM]);
}

// ---------------------------------------------------------------------------
// Kernel 3: finalize — mean(log(rowsum)), mean(log(colsum)), mean(diag).
// ---------------------------------------------------------------------------
__global__ __launch_bounds__(1024) void finalize_kernel(
    const float* __restrict__ rowsum, const float* __restrict__ colsum,
    const float* __restrict__ diagarr, float* __restrict__ out, int n) {
  __shared__ float sh[48];
  float sr = 0.0f, sc = 0.0f, sd = 0.0f;
  for (int i = threadIdx.x; i < n; i += 1024) {
    sr += logf(rowsum[i]);
    sc += logf(colsum[i]);
    sd += diagarr[i];
  }
#pragma unroll
  for (int off = 1; off < 64; off <<= 1) {
    sr += __shfl_xor(sr, off, 64);
    sc += __shfl_xor(sc, off, 64);
    sd += __shfl_xor(sd, off, 64);
  }
  const int w = threadIdx.x >> 6, lane = threadIdx.x & 63;
  if (lane == 0) { sh[w] = sr; sh[16 + w] = sc; sh[32 + w] = sd; }
  __syncthreads();
  if (threadIdx.x == 0) {
    float tr = 0.0f, tc = 0.0f, td = 0.0f;
#pragma unroll
    for (int i = 0; i < 16; ++i) {
      tr += sh[i]; tc += sh[16 + i]; td += sh[32 + i];
    }
    const float invN = 1.0f / (float)n;
    const float dm = td * INV_T * invN;   // mean diag logit
    const float lvu = tr * invN - dm;
    const float luv = tc * invN - dm;
    out[0] = 0.5f * lvu + 0.5f * luv;  // WEIGHT = 0.5
    out[1] = lvu;
    out[2] = luv;
  }
}

extern "C" void kernel_launch(void* const* d_in, const int* in_sizes, int n_in,
                              void* d_out, int out_size, void* d_ws, size_t ws_size,
                              hipStream_t stream) {
  const float* img = (const float*)d_in[0];
  const float* txt = (const float*)d_in[1];
  float* out = (float*)d_out;
  const int N = in_sizes[0] / D_DIM;  // 16384

  char* ws = (char*)d_ws;
  __hip_bfloat16* Vb = (__hip_bfloat16*)ws;
  __hip_bfloat16* Ub = (__hip_bfloat16*)(ws + (size_t)N * D_DIM * 2);
  float* rowsum = (float*)(ws + (size_t)N * D_DIM * 4);
  float* colsum = rowsum + N;
  float* diagarr = colsum + N;

  // rowsum/colsum zeroed inside normalize_kernel (ws poisoned 0xAA pre-launch)
  normalize_kernel<<<N / 4, 256, 0, stream>>>(img, txt, Vb, Ub, diagarr,
                                              rowsum, colsum);

  dim3 grid(N / BN, N / BM);
  gemm_lse_kernel<<<grid, 256, 0, stream>>>(Vb, Ub, rowsum, colsum);

  finalize_kernel<<<1, 1024, 0, stream>>>(rowsum, colsum, diagarr, out, N);
}

// Round 4
// 279.562 us; speedup vs baseline: 2.3998x; 1.0513x over previous
//
#include <hip/hip_runtime.h>
#include <hip/hip_bf16.h>

// NT-Xent (CLIP) loss, N=16384 D=256 fp32 in, 3 fp32 out.
// loss_vu = mean_i( log(sum_j exp(sim_ij)) - sim_ii ), sim = (v̂·û^T)/T
// Logits bounded by 1/T=14.29 -> no max subtraction needed for exp stability.
//
// R2: XOR-swizzled LDS (zero bank conflicts), per-row diag array. 237us.
// R3: gload_lds staging -- REGRESSED (280us): serial stage->drain->compute.
// R4: T14 via lambdas -- REGRESSED (635us): ref-capture defeated SROA,
//     staging spilled to scratch (WRITE_SIZE 910MB).
// R5: named staging scalars -- scratch fixed (16MB) but VGPR=76 proves the
//     scheduler SANK the loads below the MFMA cluster (staging regs not
//     live across compute): overlap never happened, 230us ~= R2.
// R6: pin the load cluster with sched_barrier(0) right after issue. The
//     scheduler can no longer sink them; L2 latency (~300-400cyc) drains
//     under the ds_read+MFMA phase; the vmcnt wait before the post-barrier
//     ds_write becomes ~free. Gate: VGPR must rise to ~130-150.
//     Also: K3 logf -> __logf (v_log_f32).

#define D_DIM 256
#define BM 128
#define BN 128
#define BK 64

constexpr float INV_T = 1.0f / 0.07f;
constexpr float EXP2_SCALE = 1.44269504088896340736f / 0.07f;  // log2(e)/T

typedef __bf16 bf16x8 __attribute__((ext_vector_type(8)));
typedef float f32x4 __attribute__((ext_vector_type(4)));

// ---------------------------------------------------------------------------
// Kernel 1: L2-normalize (fp32 -> bf16), one WAVE per row (4 rows/block).
//           Writes per-row diag contribution v̂_i·û_i to diagarr (no atomic).
//           Also zeroes rowsum/colsum for this row (replaces memset).
// ---------------------------------------------------------------------------
__global__ __launch_bounds__(256) void normalize_kernel(
    const float* __restrict__ img, const float* __restrict__ txt,
    __hip_bfloat16* __restrict__ Vb, __hip_bfloat16* __restrict__ Ub,
    float* __restrict__ diagarr, float* __restrict__ rowsum,
    float* __restrict__ colsum) {
  const int wave = threadIdx.x >> 6;
  const int lane = threadIdx.x & 63;
  const int row = blockIdx.x * 4 + wave;
  const size_t base = (size_t)row * D_DIM + lane * 4;

  const float4 iv = *reinterpret_cast<const float4*>(&img[base]);
  const float4 tv = *reinterpret_cast<const float4*>(&txt[base]);

  float a = iv.x * iv.x + iv.y * iv.y + iv.z * iv.z + iv.w * iv.w;
  float b = tv.x * tv.x + tv.y * tv.y + tv.z * tv.z + tv.w * tv.w;
#pragma unroll
  for (int off = 1; off < 64; off <<= 1) {
    a += __shfl_xor(a, off, 64);
    b += __shfl_xor(b, off, 64);
  }
  const float si = 1.0f / fmaxf(sqrtf(a), 1e-8f);
  const float st = 1.0f / fmaxf(sqrtf(b), 1e-8f);
  const float4 v = {iv.x * si, iv.y * si, iv.z * si, iv.w * si};
  const float4 u = {tv.x * st, tv.y * st, tv.z * st, tv.w * st};

  __hip_bfloat16 vb4[4] = {__float2bfloat16(v.x), __float2bfloat16(v.y),
                           __float2bfloat16(v.z), __float2bfloat16(v.w)};
  __hip_bfloat16 ub4[4] = {__float2bfloat16(u.x), __float2bfloat16(u.y),
                           __float2bfloat16(u.z), __float2bfloat16(u.w)};
  *reinterpret_cast<uint2*>(&Vb[base]) = *reinterpret_cast<uint2*>(vb4);
  *reinterpret_cast<uint2*>(&Ub[base]) = *reinterpret_cast<uint2*>(ub4);

  float d = v.x * u.x + v.y * u.y + v.z * u.z + v.w * u.w;
#pragma unroll
  for (int off = 1; off < 64; off <<= 1) d += __shfl_xor(d, off, 64);
  if (lane == 0) {
    diagarr[row] = d;
    rowsum[row] = 0.0f;
    colsum[row] = 0.0f;
  }
}

// ---------------------------------------------------------------------------
// Kernel 2: tiled bf16 MFMA GEMM over sim = V·U^T, online exp-sum per row
//           and per column. 128x128 tile/block, 4 waves of 64x64.
// LDS layout XOR-swizzled: 16B chunk c8 of row r stored at chunk (c8 ^ (r&7)).
//   - frag reads: 16 lanes read rows base+l15 at chunk c8a -> p=c8a^(l15&7)
//     spans 0..7 per 8 lanes -> 2 lanes/bank = free (m136).
// Staging addressing (per thread, all four 32-row groups):
//   r0 = tid>>3 (row-in-group), c8 = tid&7 (16B chunk in row).
//   group q covers rows q*32+r0; swizzle offset identical across q since
//   (q*32 + r0) & 7 == r0 & 7.
// Pipeline (T14, enforced): loads for tile t+1 issue at iteration top and
//   are PINNED there by sched_barrier(0); compute covers L2 latency;
//   ds_writes after the WAR barrier find vmcnt already drained.
// A-frag (16x16x32): A[m=lane&15][k=quad*8+j]; B symmetric (U row-major).
// C/D: col=lane&15, row=quad*4+reg (m89/m91-verified).
// ---------------------------------------------------------------------------
__global__ __launch_bounds__(256) void gemm_lse_kernel(
    const __hip_bfloat16* __restrict__ V, const __hip_bfloat16* __restrict__ U,
    float* __restrict__ rowsum, float* __restrict__ colsum) {
  __shared__ __align__(16) unsigned short As[BM * BK];  // 16 KB
  __shared__ __align__(16) unsigned short Bs[BN * BK];  // 16 KB

  const int tid = threadIdx.x;
  const int lane = tid & 63;
  const int wave = tid >> 6;
  const int wm = wave >> 1;   // wave row (0..1)
  const int wn = wave & 1;    // wave col (0..1)
  const int quad = lane >> 4;
  const int l15 = lane & 15;
  const int sw = l15 & 7;     // read-swizzle factor (= frag row & 7)
  const int ibase = blockIdx.y * BM;
  const int jbase = blockIdx.x * BN;

  // Staging address bases (see header).
  const int r0 = tid >> 3;
  const int c8 = tid & 7;
  const int dbase = r0 * BK + ((c8 ^ (r0 & 7)) << 3);
  const __hip_bfloat16* Vp =
      V + (size_t)(ibase + r0) * D_DIM + c8 * 8;
  const __hip_bfloat16* Up =
      U + (size_t)(jbase + r0) * D_DIM + c8 * 8;

  // Eight named staging registers -- live across the compute phase.
  uint4 ra0, ra1, ra2, ra3, rb0, rb1, rb2, rb3;

#define LOAD_TILE(kk)                                                      \
  ra0 = *reinterpret_cast<const uint4*>(Vp + (kk));                        \
  ra1 = *reinterpret_cast<const uint4*>(Vp + 32 * D_DIM + (kk));           \
  ra2 = *reinterpret_cast<const uint4*>(Vp + 64 * D_DIM + (kk));           \
  ra3 = *reinterpret_cast<const uint4*>(Vp + 96 * D_DIM + (kk));           \
  rb0 = *reinterpret_cast<const uint4*>(Up + (kk));                        \
  rb1 = *reinterpret_cast<const uint4*>(Up + 32 * D_DIM + (kk));           \
  rb2 = *reinterpret_cast<const uint4*>(Up + 64 * D_DIM + (kk));           \
  rb3 = *reinterpret_cast<const uint4*>(Up + 96 * D_DIM + (kk));

#define WRITE_TILE()                                                       \
  *reinterpret_cast<uint4*>(&As[dbase]) = ra0;                             \
  *reinterpret_cast<uint4*>(&As[dbase + 32 * BK]) = ra1;                   \
  *reinterpret_cast<uint4*>(&As[dbase + 64 * BK]) = ra2;                   \
  *reinterpret_cast<uint4*>(&As[dbase + 96 * BK]) = ra3;                   \
  *reinterpret_cast<uint4*>(&Bs[dbase]) = rb0;                             \
  *reinterpret_cast<uint4*>(&Bs[dbase + 32 * BK]) = rb1;                   \
  *reinterpret_cast<uint4*>(&Bs[dbase + 64 * BK]) = rb2;                   \
  *reinterpret_cast<uint4*>(&Bs[dbase + 96 * BK]) = rb3;

  f32x4 acc[4][4] = {};

  LOAD_TILE(0);
  WRITE_TILE();
  __syncthreads();

#pragma unroll
  for (int t = 0; t < 4; ++t) {
    if (t < 3) {
      LOAD_TILE((t + 1) * BK);  // issue early: latency hides under MFMA
      // Pin the loads here -- without this the scheduler sinks them below
      // the MFMA cluster to save registers (R5: VGPR=76 proved it).
      __builtin_amdgcn_sched_barrier(0);
    }

#pragma unroll
    for (int ks = 0; ks < BK; ks += 32) {
      const int c8a = (ks >> 3) + quad;          // logical 16B chunk
      const int pc = ((c8a ^ sw) << 3);          // swizzled short offset
      bf16x8 af[4], bfr[4];
#pragma unroll
      for (int mi = 0; mi < 4; ++mi)
        af[mi] = *reinterpret_cast<const bf16x8*>(
            &As[(wm * 64 + mi * 16 + l15) * BK + pc]);
#pragma unroll
      for (int ni = 0; ni < 4; ++ni)
        bfr[ni] = *reinterpret_cast<const bf16x8*>(
            &Bs[(wn * 64 + ni * 16 + l15) * BK + pc]);
#pragma unroll
      for (int mi = 0; mi < 4; ++mi)
#pragma unroll
        for (int ni = 0; ni < 4; ++ni)
          acc[mi][ni] = __builtin_amdgcn_mfma_f32_16x16x32_bf16(
              af[mi], bfr[ni], acc[mi][ni], 0, 0, 0);
    }
    __syncthreads();  // all waves done READING As/Bs (WAR guard)
    if (t < 3) {
      WRITE_TILE();   // loads landed during compute; drain is ~free
      __syncthreads();
    }
  }

  // ---- epilogue: exp + row/col reduction ----
  // acc[mi][ni][r]: row = wm*64+mi*16+quad*4+r, col = wn*64+ni*16+l15.
  // exp(acc/T) = exp2(acc * log2e/T): single mul + v_exp per element.
#pragma unroll
  for (int mi = 0; mi < 4; ++mi)
#pragma unroll
    for (int ni = 0; ni < 4; ++ni)
#pragma unroll
      for (int r = 0; r < 4; ++r)
        acc[mi][ni][r] = __builtin_amdgcn_exp2f(acc[mi][ni][r] * EXP2_SCALE);

  // Reuse As as fp32 scratch: rowbuf[128], colbuf[128].
  float* rowbuf = reinterpret_cast<float*>(As);
  float* colbuf = rowbuf + BM;
  reinterpret_cast<float*>(As)[tid] = 0.0f;  // zero 256 floats
  __syncthreads();

  // Row sums: reduce across 16 cols (lanes quad*16..quad*16+15), then the
  // two wn halves meet in LDS.
#pragma unroll
  for (int mi = 0; mi < 4; ++mi) {
#pragma unroll
    for (int r = 0; r < 4; ++r) {
      float rs = acc[mi][0][r] + acc[mi][1][r] + acc[mi][2][r] + acc[mi][3][r];
      rs += __shfl_xor(rs, 1, 64);
      rs += __shfl_xor(rs, 2, 64);
      rs += __shfl_xor(rs, 4, 64);
      rs += __shfl_xor(rs, 8, 64);
      if (l15 == 0)
        atomicAdd(&rowbuf[wm * 64 + mi * 16 + quad * 4 + r], rs);
    }
  }
  // Col sums: reduce across 16 rows (quads), two wm halves meet in LDS.
#pragma unroll
  for (int ni = 0; ni < 4; ++ni) {
    float cs = 0.0f;
#pragma unroll
    for (int mi = 0; mi < 4; ++mi)
      cs += acc[mi][ni][0] + acc[mi][ni][1] + acc[mi][ni][2] + acc[mi][ni][3];
    cs += __shfl_xor(cs, 16, 64);
    cs += __shfl_xor(cs, 32, 64);
    if (lane < 16)
      atomicAdd(&colbuf[wn * 64 + ni * 16 + l15], cs);
  }
  __syncthreads();

  if (tid < BM)
    atomicAdd(&rowsum[ibase + tid], rowbuf[tid]);
  else
    atomicAdd(&colsum[jbase + tid - BM], colbuf[tid - BM]);
}

// ---------------------------------------------------------------------------
// Kernel 3: finalize — mean(log(rowsum)), mean(log(colsum)), mean(diag).
// __logf -> v_log_f32 (+mul by ln2): ~1ulp, vastly cheaper than libm logf.
// ---------------------------------------------------------------------------
__global__ __launch_bounds__(1024) void finalize_kernel(
    const float* __restrict__ rowsum, const float* __restrict__ colsum,
    const float* __restrict__ diagarr, float* __restrict__ out, int n) {
  __shared__ float sh[48];
  float sr = 0.0f, sc = 0.0f, sd = 0.0f;
  for (int i = threadIdx.x; i < n; i += 1024) {
    sr += __logf(rowsum[i]);
    sc += __logf(colsum[i]);
    sd += diagarr[i];
  }
#pragma unroll
  for (int off = 1; off < 64; off <<= 1) {
    sr += __shfl_xor(sr, off, 64);
    sc += __shfl_xor(sc, off, 64);
    sd += __shfl_xor(sd, off, 64);
  }
  const int w = threadIdx.x >> 6, lane = threadIdx.x & 63;
  if (lane == 0) { sh[w] = sr; sh[16 + w] = sc; sh[32 + w] = sd; }
  __syncthreads();
  if (threadIdx.x == 0) {
    float tr = 0.0f, tc = 0.0f, td = 0.0f;
#pragma unroll
    for (int i = 0; i < 16; ++i) {
      tr += sh[i]; tc += sh[16 + i]; td += sh[32 + i];
    }
    const float invN = 1.0f / (float)n;
    const float dm = td * INV_T * invN;   // mean diag logit
    const float lvu = tr * invN - dm;
    const float luv = tc * invN - dm;
    out[0] = 0.5f * lvu + 0.5f * luv;  // WEIGHT = 0.5
    out[1] = lvu;
    out[2] = luv;
  }
}

extern "C" void kernel_launch(void* const* d_in, const int* in_sizes, int n_in,
                              void* d_out, int out_size, void* d_ws, size_t ws_size,
                              hipStream_t stream) {
  const float* img = (const float*)d_in[0];
  const float* txt = (const float*)d_in[1];
  float* out = (float*)d_out;
  const int N = in_sizes[0] / D_DIM;  // 16384

  char* ws = (char*)d_ws;
  __hip_bfloat16* Vb = (__hip_bfloat16*)ws;
  __hip_bfloat16* Ub = (__hip_bfloat16*)(ws + (size_t)N * D_DIM * 2);
  float* rowsum = (float*)(ws + (size_t)N * D_DIM * 4);
  float* colsum = rowsum + N;
  float* diagarr = colsum + N;

  // rowsum/colsum zeroed inside normalize_kernel (ws poisoned 0xAA pre-launch)
  normalize_kernel<<<N / 4, 256, 0, stream>>>(img, txt, Vb, Ub, diagarr,
                                              rowsum, colsum);

  dim3 grid(N / BN, N / BM);
  gemm_lse_kernel<<<grid, 256, 0, stream>>>(Vb, Ub, rowsum, colsum);

  finalize_kernel<<<1, 1024, 0, stream>>>(rowsum, colsum, diagarr, out, N);
}